// Round 3
// baseline (219.299 us; speedup 1.0000x reference)
//
#include <hip/hip_runtime.h>

// Sigmoid-attention: O = sigmoid(Q K^T / 8) V per (b,h). B*H=64, S=2048, D=64.
// R7: FUSED single kernel. R6 data falsified the prepass-coalescing theory:
// total (208us) ~= prepass (~110us, invariant to write-coalescing fix) + main
// (96us). The ws round-trip only pre-converts K/V to bf16 frags; doing the
// conversion inline costs ~150 cyc/wave/iter on a 620-cyc VALU phase, while
// K/V fp32 re-reads are L2/LLC-absorbed (HBM at 6-10% peak). So: delete the
// prepass + ws entirely; keep R6 main's structure (2-chunk super-iterations,
// double-buffered LDS, setprio around MFMA clusters), load fp32 K/V direct.
// Frag mappings identical to the verified fallback/main pair.

typedef __bf16 bf16_t;
typedef __attribute__((ext_vector_type(8))) __bf16 bf16x8;
typedef __attribute__((ext_vector_type(4))) float  f32x4;

#if defined(__HIP_DEVICE_COMPILE__) && __has_builtin(__builtin_amdgcn_exp2f)
#define FAST_EXP2(x) __builtin_amdgcn_exp2f(x)
#else
#define FAST_EXP2(x) exp2f(x)
#endif
#if defined(__HIP_DEVICE_COMPILE__) && __has_builtin(__builtin_amdgcn_rcpf)
#define FAST_RCP(x) __builtin_amdgcn_rcpf(x)
#else
#define FAST_RCP(x) (1.0f/(x))
#endif

static constexpr int SEQ = 2048;
static constexpr int DH  = 64;
static constexpr int KB  = 32;           // keys per chunk
static constexpr int NIT = SEQ / KB;     // 64 chunks
static constexpr int NIT2 = NIT / 2;     // 32 super-iterations (2 chunks each)
static constexpr int QPW = 32;
static constexpr int QPB = 128;
static constexpr int CHUNK = 4096;       // bf16 per chunk in LDS (K 2048 + V 2048)

// LDS chunk layout (identical to R5/R6 ws image):
//   [0,2048)   K frags, slot t (t = f*64+lane, f = ks*2+dh):
//       slot(f,lane,j) = K[kb + ks*16 + (lane&15)][dh*32 + (lane>>4)*8 + j]
//   [2048,4096) V frags, slot t (t = dt*64+lane), k-permuted (kappa):
//       slot(dt,lane,j) = V[kb + kappa(lane>>4,j)][dt*16 + (lane&15)]
//       kappa(g4,j) = (j>>2)*16 + g4*4 + (j&3)
// The kappa permutation matches the PV A-fragment k-slot order of the sigmoid
// output, so P feeds mfma_16x16x32 straight from registers.

__global__ __launch_bounds__(256, 4)
void sigattn_fused(const float* __restrict__ Qg, const float* __restrict__ Kg,
                   const float* __restrict__ Vg, float* __restrict__ Og)
{
    // double-buffered, TWO chunks per buffer (64 keys / barrier): 16KB x2
    __shared__ __align__(16) bf16_t buf[2][2 * CHUNK];

    const int t    = threadIdx.x;
    const int wave = t >> 6;
    const int lane = t & 63;
    const int c16  = lane & 15;
    const int g4   = lane >> 4;

    const int bh    = blockIdx.x;
    const int qtile = blockIdx.y;

    const size_t hbase = (size_t)bh * SEQ * DH;
    const float* Qp = Qg + hbase;
    const float* Kp = Kg + hbase;
    const float* Vp = Vg + hbase;
    float*       Op = Og + hbase;

    const int qwave = qtile * QPB + wave * QPW;

    // Q fragments (pre-scaled by -log2(e)/8): B-frag layout
    const float qscale = -0.125f * 1.44269504088896340736f;
    bf16x8 qf[2][2];
    #pragma unroll
    for (int qs = 0; qs < 2; ++qs) {
        #pragma unroll
        for (int dh = 0; dh < 2; ++dh) {
            const float* p = Qp + (size_t)(qwave + qs * 16 + c16) * DH + dh * 32 + g4 * 8;
            f32x4 a = *(const f32x4*)p;
            f32x4 b = *(const f32x4*)(p + 4);
            bf16x8 f;
            f[0] = (bf16_t)(a.x * qscale); f[1] = (bf16_t)(a.y * qscale);
            f[2] = (bf16_t)(a.z * qscale); f[3] = (bf16_t)(a.w * qscale);
            f[4] = (bf16_t)(b.x * qscale); f[5] = (bf16_t)(b.y * qscale);
            f[6] = (bf16_t)(b.z * qscale); f[7] = (bf16_t)(b.w * qscale);
            qf[qs][dh] = f;
        }
    }

    // fp32 staging regs for two chunks; converted to bf16 at LDS-store time.
    // All indices compile-time (full unroll) -> stays in registers (rule #20).
    f32x4 kst[2][2];
    float vst[2][8];
    auto issue_loads2 = [&](int su) {   // load super-chunk su (chunks 2su, 2su+1)
        #pragma unroll
        for (int c = 0; c < 2; ++c) {
            const int kb0 = (2 * su + c) * KB;
            // K: thread t owns frag slot t (f = wave): 32B contiguous per thread
            const float* pk = Kp + (size_t)(kb0 + (wave >> 1) * 16 + c16) * DH
                                 + (wave & 1) * 32 + g4 * 8;
            kst[c][0] = *(const f32x4*)pk;
            kst[c][1] = *(const f32x4*)(pk + 4);
            // V: thread t owns frag slot t (dt = wave); 8 scalar gathers, each
            // instruction covers 4 rows x 16 consecutive cols = 64B segments
            const float* pv = Vp + (size_t)(kb0 + g4 * 4) * DH + wave * 16 + c16;
            #pragma unroll
            for (int h = 0; h < 2; ++h)
                #pragma unroll
                for (int j = 0; j < 4; ++j)
                    vst[c][h * 4 + j] = pv[(size_t)(h * 16 + j) * DH];
        }
    };
    auto store2 = [&](int nb) {         // convert + publish into buf[nb]
        #pragma unroll
        for (int c = 0; c < 2; ++c) {
            bf16x8 k8;
            #pragma unroll
            for (int i = 0; i < 4; ++i) {
                k8[i]     = (bf16_t)kst[c][0][i];
                k8[4 + i] = (bf16_t)kst[c][1][i];
            }
            *(bf16x8*)&buf[nb][c * CHUNK + t * 8] = k8;
            bf16x8 v8;
            #pragma unroll
            for (int j = 0; j < 8; ++j) v8[j] = (bf16_t)vst[c][j];
            *(bf16x8*)&buf[nb][c * CHUNK + 2048 + t * 8] = v8;
        }
    };

    issue_loads2(0);
    store2(0);

    f32x4 acc[2][4] = {};   // [qs][dt], C-layout: row=q(g4*4+r), col=d(c16)

    for (int su = 0; su < NIT2; ++su) {
        const int cur = su & 1;
        __syncthreads();                         // buf[cur] published; prev reads done
        if (su + 1 < NIT2) issue_loads2(su + 1); // next super-chunk fp32 -> regs

        #pragma unroll
        for (int h = 0; h < 2; ++h) {
            const bf16_t* base = &buf[cur][h * CHUNK];
            bf16x8 kf[4], vf[4];
            #pragma unroll
            for (int f = 0; f < 4; ++f) kf[f] = *(const bf16x8*)&base[(f * 64 + lane) * 8];
            #pragma unroll
            for (int f = 0; f < 4; ++f) vf[f] = *(const bf16x8*)&base[2048 + (f * 64 + lane) * 8];

            #pragma unroll
            for (int qs = 0; qs < 2; ++qs) {
                // S^T = K*Q^T: lane holds keys {g4*4+r} (s0) and {16+g4*4+r} (s1), q=c16
                f32x4 s0 = {0.f, 0.f, 0.f, 0.f}, s1 = {0.f, 0.f, 0.f, 0.f};
                __builtin_amdgcn_s_setprio(1);
                s0 = __builtin_amdgcn_mfma_f32_16x16x32_bf16(kf[0], qf[qs][0], s0, 0, 0, 0);
                s0 = __builtin_amdgcn_mfma_f32_16x16x32_bf16(kf[1], qf[qs][1], s0, 0, 0, 0);
                s1 = __builtin_amdgcn_mfma_f32_16x16x32_bf16(kf[2], qf[qs][0], s1, 0, 0, 0);
                s1 = __builtin_amdgcn_mfma_f32_16x16x32_bf16(kf[3], qf[qs][1], s1, 0, 0, 0);
                __builtin_amdgcn_s_setprio(0);
                // sigmoid -> bf16x8 = A-frag of 16x16x32 PV; A k-slot g4*8+j holds
                // key kappa(g4,j), matching the V fragment permutation.
                bf16x8 p8;
                #pragma unroll
                for (int r = 0; r < 4; ++r) p8[r]     = (bf16_t)FAST_RCP(1.0f + FAST_EXP2(s0[r]));
                #pragma unroll
                for (int r = 0; r < 4; ++r) p8[4 + r] = (bf16_t)FAST_RCP(1.0f + FAST_EXP2(s1[r]));
                __builtin_amdgcn_s_setprio(1);
                #pragma unroll
                for (int dt = 0; dt < 4; ++dt)
                    acc[qs][dt] = __builtin_amdgcn_mfma_f32_16x16x32_bf16(p8, vf[dt], acc[qs][dt], 0, 0, 0);
                __builtin_amdgcn_s_setprio(0);
            }
        }

        if (su + 1 < NIT2) store2(cur ^ 1);      // convert + publish next super-chunk
    }

    #pragma unroll
    for (int qs = 0; qs < 2; ++qs) {
        const int q0 = qwave + qs * 16 + g4 * 4;
        #pragma unroll
        for (int r = 0; r < 4; ++r) {
            float* po = Op + (size_t)(q0 + r) * DH + c16;
            po[0]  = acc[qs][0][r];
            po[16] = acc[qs][1][r];
            po[32] = acc[qs][2][r];
            po[48] = acc[qs][3][r];
        }
    }
}

extern "C" void kernel_launch(void* const* d_in, const int* in_sizes, int n_in,
                              void* d_out, int out_size, void* d_ws, size_t ws_size,
                              hipStream_t stream)
{
    const float* q = (const float*)d_in[0];
    const float* k = (const float*)d_in[1];
    const float* v = (const float*)d_in[2];
    float* o = (float*)d_out;
    (void)d_ws; (void)ws_size;
    // grid x = bh keeps blocks sharing a head's K/V spread so each XCD touches
    // only heads ≡ xcd (mod 8): 16MB fp32 working set/XCD (best orientation).
    sigattn_fused<<<dim3(64, SEQ / QPB), dim3(256), 0, stream>>>(q, k, v, o);
}